// Round 4
// baseline (257.760 us; speedup 1.0000x reference)
//
#include <hip/hip_runtime.h>
#include <hip/hip_bf16.h>
#include <stdint.h>

// QuantizedLinear: out[16,11008] = x[16,4096] @ ((W - zp)*scale)^T
// W arrives as int32 (harness: integer -> const int*) = 180 MB -> HBM-bound,
// qgemm floor ~29 us. Total dur_us also carries ~210 us of harness re-poison
// fills (top-5 rocprof rows) we cannot control.
// v4: 8-row tiles (1376 blocks, 18.7 KB LDS -> 8 blocks/CU) for smoother
// block pipelining + 2x MLP headroom. MFMA cols 8-15 alias cols 0-7 (free at
// 3% MfmaUtil). Wave-private double-buffered global_load_lds, swizzle encoded
// in the GLOBAL source address (LDS dest is hw-fixed lane*16).

#define M_TOK 16
#define K_DIM 4096
#define N_OUT 11008

typedef int v4i __attribute__((ext_vector_type(4)));

#define GLOAD_LDS16(g, l)                                               \
  __builtin_amdgcn_global_load_lds(                                     \
      (const __attribute__((address_space(1))) void*)(g),               \
      (__attribute__((address_space(3))) void*)(l), 16, 0, 0)

// ---------------- Kernel 1: per-token quantization of x ----------------
// x ~= s1 * (xh + xl/256), 15-bit effective precision. PASSED R2/R3.
__global__ __launch_bounds__(256) void quant_x_kernel(
    const float* __restrict__ x, int8_t* __restrict__ xh,
    int8_t* __restrict__ xl, float* __restrict__ s1_out,
    float* __restrict__ sumx_out) {
  const int t = blockIdx.x;
  const int tid = threadIdx.x;
  const float4* xv = (const float4*)(x + (long)t * K_DIM) + tid * 4;

  float vals[16];
  float m = 0.0f, s = 0.0f;
#pragma unroll
  for (int j = 0; j < 4; ++j) {
    float4 f = xv[j];
    vals[j * 4 + 0] = f.x; vals[j * 4 + 1] = f.y;
    vals[j * 4 + 2] = f.z; vals[j * 4 + 3] = f.w;
    m = fmaxf(m, fmaxf(fmaxf(fabsf(f.x), fabsf(f.y)),
                       fmaxf(fabsf(f.z), fabsf(f.w))));
    s += f.x + f.y + f.z + f.w;
  }
#pragma unroll
  for (int off = 32; off > 0; off >>= 1) {
    m = fmaxf(m, __shfl_xor(m, off));
    s += __shfl_xor(s, off);
  }
  __shared__ float lm[4], ls[4];
  const int w = tid >> 6;
  if ((tid & 63) == 0) { lm[w] = m; ls[w] = s; }
  __syncthreads();
  m = fmaxf(fmaxf(lm[0], lm[1]), fmaxf(lm[2], lm[3]));
  s = ls[0] + ls[1] + ls[2] + ls[3];

  const float s1 = (m > 0.0f) ? (m * (1.0f / 127.0f)) : 1.0f;
  const float inv = 1.0f / s1;
  if (tid == 0) { s1_out[t] = s1; sumx_out[t] = s; }

  int hq[16], lq[16];
#pragma unroll
  for (int j = 0; j < 16; ++j) {
    float xf = vals[j];
    float h = rintf(xf * inv);
    h = fminf(fmaxf(h, -127.0f), 127.0f);
    float resid = xf - h * s1;
    float l = rintf(resid * inv * 256.0f);
    l = fminf(fmaxf(l, -128.0f), 127.0f);
    hq[j] = (int)h;
    lq[j] = (int)l;
  }
  int4 hv, lv;
  int* hp = (int*)&hv;
  int* lp = (int*)&lv;
#pragma unroll
  for (int d = 0; d < 4; ++d) {
    uint32_t hw = 0, lw = 0;
#pragma unroll
    for (int j = 0; j < 4; ++j) {
      hw |= (uint32_t)(hq[d * 4 + j] & 0xff) << (8 * j);
      lw |= (uint32_t)(lq[d * 4 + j] & 0xff) << (8 * j);
    }
    hp[d] = (int)hw;
    lp[d] = (int)lw;
  }
  ((int4*)xh)[(long)t * 256 + tid] = hv;
  ((int4*)xl)[(long)t * 256 + tid] = lv;
}

// ---------------- Kernel 2: weight-streaming i8 MFMA GEMM ----------------
// 1376 blocks x 256 thr (4 waves). Block owns 8 W rows; wave w owns the
// interleaved k-granule [s*256 + w*64, +64) int32 per stage s (16 stages).
// Per stage: 2x global_load_lds(16B) stage 2 KB into wave-private double
// buffer; B fragment packed from low bytes; cols 8-15 of the 16x16 MFMA
// duplicate cols 0-7 (row aliased via n&7). No __syncthreads in K-loop.
__global__ __launch_bounds__(256) void qgemm_kernel(
    const int* __restrict__ W, const int8_t* __restrict__ xh,
    const int8_t* __restrict__ xl, const float* __restrict__ s1,
    const float* __restrict__ sumx, const float* __restrict__ scale_p,
    const int* __restrict__ zp_p, float* __restrict__ out) {
  const int tid = threadIdx.x;
  const int lane = tid & 63;
  const int w = tid >> 6;          // wave id = K split
  const int obase = blockIdx.x * 8;
  const int n = lane & 15;         // A: token / B: output col
  const int g = lane >> 4;         // k sub-group within 64-k chunk
  const int r = n & 7;             // W row within 8-row tile (cols alias)

  __shared__ int wlds[2][4][512];  // [buf][wave][8 rows * 64 int32] = 16 KB

  // Staging source: instr j (0,1), this lane fills LDS slot j*64+lane, which
  // holds (row_l = j*4 + (lane>>4), stored-slot sq = lane&15); swizzled
  // content q = sq ^ row_l. Global int32 offset: row*4096 + w*64 + q*4.
  {
    // nothing
  }
  const int rl0 = 0 * 4 + g;            // instr 0 local row
  const int rl1 = 1 * 4 + g;            // instr 1 local row
  const int* gj0 = W + (long)(obase + rl0) * K_DIM + w * 64 + ((n ^ rl0) & 15) * 4;
  const int* gj1 = W + (long)(obase + rl1) * K_DIM + w * 64 + ((n ^ rl1) & 15) * 4;

  // ds_read: read t wants (row r, q = g*4+t), stored at r*16 + ((g*4+t)^r).
  const int Q0 = (g * 4) ^ r;
  const int r0 = r * 64 + (Q0 ^ 0) * 4;
  const int r1 = r * 64 + (Q0 ^ 1) * 4;
  const int r2 = r * 64 + (Q0 ^ 2) * 4;
  const int r3 = r * 64 + (Q0 ^ 3) * 4;

  const v4i* Ah = (const v4i*)(xh + (long)n * K_DIM + w * 64 + g * 16);
  const v4i* Al = (const v4i*)(xl + (long)n * K_DIM + w * 64 + g * 16);

  v4i accH = {0, 0, 0, 0};
  v4i accL = {0, 0, 0, 0};

  // Prologue: stage 0 -> buf 0
  GLOAD_LDS16(gj0, &wlds[0][w][0]);
  GLOAD_LDS16(gj1, &wlds[0][w][256]);

#pragma unroll
  for (int s = 0; s < 16; ++s) {
    const int b = s & 1;
    if (s + 1 < 16) {  // prefetch next stage into other buffer
      const int soff = (s + 1) * 256;
      GLOAD_LDS16(gj0 + soff, &wlds[b ^ 1][w][0]);
      GLOAD_LDS16(gj1 + soff, &wlds[b ^ 1][w][256]);
    }
    v4i ah = Ah[s * 16];
    v4i al = Al[s * 16];

    v4i q0 = *(const v4i*)&wlds[b][w][r0];
    v4i q1 = *(const v4i*)&wlds[b][w][r1];
    v4i q2 = *(const v4i*)&wlds[b][w][r2];
    v4i q3 = *(const v4i*)&wlds[b][w][r3];

    v4i bf;
    bf[0] = (int)(((uint32_t)q0[0] & 0xffu) | (((uint32_t)q0[1] & 0xffu) << 8) |
                  (((uint32_t)q0[2] & 0xffu) << 16) | ((uint32_t)q0[3] << 24));
    bf[1] = (int)(((uint32_t)q1[0] & 0xffu) | (((uint32_t)q1[1] & 0xffu) << 8) |
                  (((uint32_t)q1[2] & 0xffu) << 16) | ((uint32_t)q1[3] << 24));
    bf[2] = (int)(((uint32_t)q2[0] & 0xffu) | (((uint32_t)q2[1] & 0xffu) << 8) |
                  (((uint32_t)q2[2] & 0xffu) << 16) | ((uint32_t)q2[3] << 24));
    bf[3] = (int)(((uint32_t)q3[0] & 0xffu) | (((uint32_t)q3[1] & 0xffu) << 8) |
                  (((uint32_t)q3[2] & 0xffu) << 16) | ((uint32_t)q3[3] << 24));

    accH = __builtin_amdgcn_mfma_i32_16x16x64_i8(ah, bf, accH, 0, 0, 0);
    accL = __builtin_amdgcn_mfma_i32_16x16x64_i8(al, bf, accL, 0, 0, 0);
  }

  // Epilogue: 4-way K reduction. C layout: col = lane&15, row(token) =
  // g*4 + reg. Only cols 0-7 are unique (8-15 duplicates) -> lanes n<8 write.
  __shared__ float red[4][16 * 9];
  if (n < 8) {
#pragma unroll
    for (int rr = 0; rr < 4; ++rr) {
      float f = (float)accH[rr] + (float)accL[rr] * (1.0f / 256.0f);
      int t = g * 4 + rr;
      red[w][t * 9 + n] = f;
    }
  }
  __syncthreads();

  if (tid < 128) {
    const int t = tid >> 3;
    const int col = tid & 7;
    float sum = red[0][t * 9 + col] + red[1][t * 9 + col] +
                red[2][t * 9 + col] + red[3][t * 9 + col];
    const float sc = scale_p[0];
    const float zp = (float)zp_p[0];
    float o = sc * (s1[t] * sum) - sc * zp * sumx[t];
    out[(long)t * N_OUT + obase + col] = o;
  }
}

extern "C" void kernel_launch(void* const* d_in, const int* in_sizes, int n_in,
                              void* d_out, int out_size, void* d_ws,
                              size_t ws_size, hipStream_t stream) {
  const float* x = (const float*)d_in[0];
  const int* Wq = (const int*)d_in[1];  // integer inputs come as int32
  const float* scale_p = (const float*)d_in[2];
  const int* zp_p = (const int*)d_in[3];
  float* out = (float*)d_out;

  int8_t* xh = (int8_t*)d_ws;
  int8_t* xl = xh + (long)M_TOK * K_DIM;
  float* s1 = (float*)(xl + (long)M_TOK * K_DIM);
  float* sumx = s1 + M_TOK;

  quant_x_kernel<<<M_TOK, 256, 0, stream>>>(x, xh, xl, s1, sumx);
  qgemm_kernel<<<N_OUT / 8, 256, 0, stream>>>(Wq, xh, xl, s1, sumx, scale_p,
                                              zp_p, out);
}